// Round 8
// baseline (378.148 us; speedup 1.0000x reference)
//
#include <hip/hip_runtime.h>
#include <hip/hip_bf16.h>

#define NB_OBJ   5
#define DIM_BODY 10
#define DIM_OBJ  15
#define N_PERM   20
#define HID      256
#define DMP      128
#define ACT      4
#define BATCH    32768
#define GOAL_DIM 30
#define DIN      19
#define OBS_LEN  85
#define TB       2                 // batch elements per block
#define MROWS    40                // TB * N_PERM
#define MR       48                // padded to 3 M-tiles
#define QKROWS   52                // stage-5 tile2 for bi=1 reads rows up to 51

typedef __hip_bfloat16 bf16;
typedef __attribute__((ext_vector_type(8))) short s16x8;   // 8 bf16 = 4 VGPRs
typedef __attribute__((ext_vector_type(4))) short s16x4;   // 4 bf16 = 8 B
typedef __attribute__((ext_vector_type(4))) float f32x4;

#define MFMA16(a, b, c) __builtin_amdgcn_mfma_f32_16x16x32_bf16((a), (b), (c), 0, 0, 0)

// ---- packed-weight offsets in d_ws (bf16 elements) ----
// tiled layout: [nt][kt][c(4)][n16(16)][j(8)], value = W[kt*32+c*8+j][nt*16+n16]
#define OFF_W1   0        // NT=16, KT=1  -> 8192 (row 19 = b1: bias folded)
#define OFF_W2   8192     // NT=8,  KT=8  -> 32768
#define OFF_WQ   40960    // NT=8,  KT=4  -> 16384
#define OFF_WK   57344
#define OFF_WV   73728
#define OFF_WR   90112    // NT=16, KT=4  -> 32768
#define PACK_TOTAL 122880

__device__ __forceinline__ float b2f(bf16 x) { return __bfloat162float(x); }
__device__ __forceinline__ bf16  f2b(float x) { return __float2bfloat16(x); }

// XOR block swizzle: element [m][k] lives at column ((k>>3) ^ (m&bprm))*8 + (k&7)
__device__ __forceinline__ s16x8 frag_lds(const bf16* base, int m, int stride, int kof, int bprm) {
    int phys = (((kof >> 3) ^ (m & bprm)) << 3);
    return *(const s16x8*)(base + m * stride + phys);
}

// C^T epilogue: lane owns fixed m, regs r = 4 consecutive n -> one b64 write
__device__ __forceinline__ void store_c4(bf16* base, int m, int stride, int n0,
                                         int bprm, f32x4 acc, f32x4 bs, bool do_relu) {
    s16x4 w;
    #pragma unroll
    for (int r = 0; r < 4; ++r) {
        float v = acc[r] + bs[r];
        if (do_relu) v = fmaxf(v, 0.f);
        bf16 t = f2b(v);
        w[r] = *(const short*)&t;
    }
    int blk = ((n0 >> 3) ^ (m & bprm));
    *(s16x4*)(base + m * stride + blk * 8 + (n0 & 7)) = w;
}

// ================= prepack: fp32 weights -> bf16 fragment-tiled layout =================
__device__ __forceinline__ void pack_tiled(const float* __restrict__ W, int Kact, int N,
                                           int KT, bf16* __restrict__ dst, int idx) {
    int tile = idx >> 9;
    int r    = idx & 511;
    int kt   = tile % KT, nt = tile / KT;
    int c    = r >> 7;
    int rem  = r & 127;
    int n16  = rem >> 3, j = rem & 7;
    int k    = kt * 32 + c * 8 + j;
    float v  = (k < Kact) ? W[k * N + nt * 16 + n16] : 0.f;
    dst[idx] = __float2bfloat16(v);
}

__global__ __launch_bounds__(256) void prepack_kernel(
    const float* __restrict__ W1, const float* __restrict__ b1,
    const float* __restrict__ W2,
    const float* __restrict__ Wq, const float* __restrict__ Wk,
    const float* __restrict__ Wv, const float* __restrict__ Wr,
    bf16* __restrict__ ws) {
    int idx = blockIdx.x * 256 + threadIdx.x;
    if (idx < 8192) {               // W1 with bias folded into k=19
        int nt = idx >> 9, r = idx & 511;
        int c = r >> 7, rem = r & 127, n16 = rem >> 3, j = rem & 7;
        int k = c * 8 + j, n = nt * 16 + n16;
        float v = (k < DIN) ? W1[k * HID + n] : (k == DIN ? b1[n] : 0.f);
        ws[OFF_W1 + idx] = __float2bfloat16(v);
    }
    else if (idx < 40960)  pack_tiled(W2, 256, 128, 8, ws + OFF_W2, idx - 8192);
    else if (idx < 57344)  pack_tiled(Wq, 128, 128, 4, ws + OFF_WQ, idx - 40960);
    else if (idx < 73728)  pack_tiled(Wk, 128, 128, 4, ws + OFF_WK, idx - 57344);
    else if (idx < 90112)  pack_tiled(Wv, 128, 128, 4, ws + OFF_WV, idx - 73728);
    else if (idx < PACK_TOTAL) pack_tiled(Wr, 128, 256, 4, ws + OFF_WR, idx - 90112);
}

// ================= main fused kernel =================
// LDS: RegA 12,288 + RegB 26,624 + RegC 12,288 = 51,200 B -> 3 blocks/CU
__global__ __launch_bounds__(256, 3) void actor_main(
    const float* __restrict__ obs, const float* __restrict__ ag, const float* __restrict__ g,
    const float* __restrict__ b2v,
    const float* __restrict__ bqv, const float* __restrict__ bkv, const float* __restrict__ bvv,
    const float* __restrict__ brv,
    const float* __restrict__ Wm, const float* __restrict__ bm,
    const float* __restrict__ Wsc, const float* __restrict__ bsv,
    const int* __restrict__ edges, const int* __restrict__ pred_ids,
    const bf16* __restrict__ wp, float* __restrict__ out)
{
    const int b0   = blockIdx.x * TB;
    const int tid  = threadIdx.x;
    const int lane = tid & 63;
    const int wav  = tid >> 6;
    const int l15  = lane & 15;
    const int lq   = lane >> 4;

    __shared__ __align__(16) union {              // 12,288 B
        struct {
            float obs_[TB][OBS_LEN];
            float dg[TB][GOAL_DIM];
            int   edg[N_PERM * 2];
            int   prd[N_PERM * 3];
            bf16  inp[MR][40];                    // K pad 19->32 (+1.0 bias col), stride 40
        } a;                                      // 5,160 B (dead after MLP1)
        bf16 v[MR][DMP];                          // 12,288 B (swizzled, written at QKV)
    } rA;
    __shared__ __align__(16) union {              // 26,624 B
        bf16 hall[MR][HID];                       // 24,576 (dead after MLP2)
        struct { bf16 q[QKROWS][DMP]; bf16 k[QKROWS][DMP]; } qk;
    } rB;
    __shared__ __align__(16) union {              // 12,288 B
        bf16 x[MR][DMP];                          // 12,288 (dead after QKV)
        struct {
            union { float sc[TB][N_PERM][N_PERM]; float red[16][17]; } s;
            float cs[TB][N_PERM];
            bf16  pooled[16][DMP];                // swizzled; rows TB..15 zeroed
            float hr[TB][HID];
        } p;                                      // 9,504 B
    } rC;

    const f32x4 zf = {0.f, 0.f, 0.f, 0.f};

    // ---- stage 0: inputs -> LDS ----
    if (tid < TB * OBS_LEN)  ((float*)rA.a.obs_)[tid] = obs[b0 * OBS_LEN + tid];
    if (tid < TB * GOAL_DIM) ((float*)rA.a.dg)[tid]   = g[b0 * GOAL_DIM + tid] - ag[b0 * GOAL_DIM + tid];
    if (tid < N_PERM * 2)    rA.a.edg[tid] = edges[tid];
    if (tid < N_PERM * 3)    rA.a.prd[tid] = pred_ids[tid];
    __syncthreads();

    // ---- stage 1: build 48 x 32 edge inputs (col 19 = 1.0 bias; pad rows 0) ----
    for (int idx = tid; idx < MR * 32; idx += 256) {
        int m = idx >> 5, c = idx & 31;
        float v = 0.f;
        if (m < MROWS) {
            int bi = m / N_PERM, p = m - bi * N_PERM;
            if      (c < 10) v = rA.a.obs_[bi][c];
            else if (c < 13) v = rA.a.dg[bi][rA.a.prd[p * 3 + (c - 10)]];
            else if (c < 16) v = rA.a.obs_[bi][DIM_BODY + rA.a.edg[p * 2 + 0] * DIM_OBJ + (c - 13)];
            else if (c < 19) v = rA.a.obs_[bi][DIM_BODY + rA.a.edg[p * 2 + 1] * DIM_OBJ + (c - 16)];
            else if (c == 19) v = 1.0f;           // bias row of W1
        }
        rA.a.inp[m][c] = f2b(v);
    }
    __syncthreads();

    // ---- stage 2: MLP1 (19->256). wave w: nt in [4w,4w+4), mt 0..2 ----
    {
        s16x8 xfr[3];
        #pragma unroll
        for (int mt = 0; mt < 3; ++mt)
            xfr[mt] = *(const s16x8*)(&rA.a.inp[mt * 16 + l15][lq * 8]);
        #pragma unroll
        for (int ntl = 0; ntl < 4; ++ntl) {
            int nt = wav * 4 + ntl;
            s16x8 wfr = *(const s16x8*)(wp + OFF_W1 + nt * 512 + (lq * 16 + l15) * 8);
            #pragma unroll
            for (int mt = 0; mt < 3; ++mt) {
                f32x4 acc = MFMA16(wfr, xfr[mt], zf);
                store_c4(&rB.hall[0][0], mt * 16 + l15, HID, nt * 16 + lq * 4, 31, acc, zf, true);
            }
        }
    }
    __syncthreads();

    // ---- stage 3: MLP2 (256->128). wave w: nt {2w,2w+1}, KT=8 ----
    {
        int nt0 = wav * 2, nt1 = nt0 + 1;
        f32x4 a0[3], a1[3];
        #pragma unroll
        for (int mt = 0; mt < 3; ++mt) { a0[mt] = zf; a1[mt] = zf; }
        #pragma unroll
        for (int kt = 0; kt < 8; ++kt) {
            s16x8 wf0 = *(const s16x8*)(wp + OFF_W2 + (nt0 * 8 + kt) * 512 + (lq * 16 + l15) * 8);
            s16x8 wf1 = *(const s16x8*)(wp + OFF_W2 + (nt1 * 8 + kt) * 512 + (lq * 16 + l15) * 8);
            #pragma unroll
            for (int mt = 0; mt < 3; ++mt) {
                s16x8 a = frag_lds(&rB.hall[0][0], mt * 16 + l15, HID, kt * 32 + lq * 8, 31);
                a0[mt] = MFMA16(wf0, a, a0[mt]);
                a1[mt] = MFMA16(wf1, a, a1[mt]);
            }
        }
        f32x4 bs0 = *(const f32x4*)(b2v + nt0 * 16 + lq * 4);
        f32x4 bs1 = *(const f32x4*)(b2v + nt1 * 16 + lq * 4);
        #pragma unroll
        for (int mt = 0; mt < 3; ++mt) {
            int m = mt * 16 + l15;
            store_c4(&rC.x[0][0], m, DMP, nt0 * 16 + lq * 4, 15, a0[mt], bs0, true);
            store_c4(&rC.x[0][0], m, DMP, nt1 * 16 + lq * 4, 15, a1[mt], bs1, true);
        }
    }
    __syncthreads();   // hall dead; x visible

    // ---- stage 4: QKV fused (one x-fragment read feeds 6 accumulators) ----
    {
        int nt0 = wav * 2, nt1 = nt0 + 1;
        f32x4 aq0[3], aq1[3], ak0[3], ak1[3], av0[3], av1[3];
        #pragma unroll
        for (int mt = 0; mt < 3; ++mt) {
            aq0[mt] = zf; aq1[mt] = zf; ak0[mt] = zf;
            ak1[mt] = zf; av0[mt] = zf; av1[mt] = zf;
        }
        #pragma unroll
        for (int kt = 0; kt < 4; ++kt) {
            int fo = (lq * 16 + l15) * 8;
            s16x8 wq0 = *(const s16x8*)(wp + OFF_WQ + (nt0 * 4 + kt) * 512 + fo);
            s16x8 wq1 = *(const s16x8*)(wp + OFF_WQ + (nt1 * 4 + kt) * 512 + fo);
            s16x8 wk0 = *(const s16x8*)(wp + OFF_WK + (nt0 * 4 + kt) * 512 + fo);
            s16x8 wk1 = *(const s16x8*)(wp + OFF_WK + (nt1 * 4 + kt) * 512 + fo);
            s16x8 wv0 = *(const s16x8*)(wp + OFF_WV + (nt0 * 4 + kt) * 512 + fo);
            s16x8 wv1 = *(const s16x8*)(wp + OFF_WV + (nt1 * 4 + kt) * 512 + fo);
            #pragma unroll
            for (int mt = 0; mt < 3; ++mt) {
                s16x8 a = frag_lds(&rC.x[0][0], mt * 16 + l15, DMP, kt * 32 + lq * 8, 15);
                aq0[mt] = MFMA16(wq0, a, aq0[mt]);  aq1[mt] = MFMA16(wq1, a, aq1[mt]);
                ak0[mt] = MFMA16(wk0, a, ak0[mt]);  ak1[mt] = MFMA16(wk1, a, ak1[mt]);
                av0[mt] = MFMA16(wv0, a, av0[mt]);  av1[mt] = MFMA16(wv1, a, av1[mt]);
            }
        }
        f32x4 bq0 = *(const f32x4*)(bqv + nt0 * 16 + lq * 4);
        f32x4 bq1 = *(const f32x4*)(bqv + nt1 * 16 + lq * 4);
        f32x4 bk0 = *(const f32x4*)(bkv + nt0 * 16 + lq * 4);
        f32x4 bk1 = *(const f32x4*)(bkv + nt1 * 16 + lq * 4);
        f32x4 bv0 = *(const f32x4*)(bvv + nt0 * 16 + lq * 4);
        f32x4 bv1 = *(const f32x4*)(bvv + nt1 * 16 + lq * 4);
        #pragma unroll
        for (int mt = 0; mt < 3; ++mt) {
            int m = mt * 16 + l15;
            store_c4(&rB.qk.q[0][0], m, DMP, nt0 * 16 + lq * 4, 15, aq0[mt], bq0, false);
            store_c4(&rB.qk.q[0][0], m, DMP, nt1 * 16 + lq * 4, 15, aq1[mt], bq1, false);
            store_c4(&rB.qk.k[0][0], m, DMP, nt0 * 16 + lq * 4, 15, ak0[mt], bk0, false);
            store_c4(&rB.qk.k[0][0], m, DMP, nt1 * 16 + lq * 4, 15, ak1[mt], bk1, false);
            store_c4(&rA.v[0][0],    m, DMP, nt0 * 16 + lq * 4, 15, av0[mt], bv0, false);
            store_c4(&rA.v[0][0],    m, DMP, nt1 * 16 + lq * 4, 15, av1[mt], bv1, false);
        }
    }
    __syncthreads();

    // ---- stage 5: scores = q k^T / sqrt(128). waves 0-1 = batch elems ----
    if (wav < TB) {
        const int bi = wav;
        const int r0 = bi * N_PERM;
        const bf16* qb = &rB.qk.q[0][0];
        const bf16* kb = &rB.qk.k[0][0];
        f32x4 c00 = zf, c01 = zf, c10 = zf, c11 = zf;
        #pragma unroll
        for (int kt = 0; kt < 4; ++kt) {
            int kof = kt * 32 + lq * 8;
            s16x8 a0 = frag_lds(qb, r0 + l15,      DMP, kof, 15);
            s16x8 a1 = frag_lds(qb, r0 + 16 + l15, DMP, kof, 15);
            s16x8 k0 = frag_lds(kb, r0 + l15,      DMP, kof, 15);
            s16x8 k1 = frag_lds(kb, r0 + 16 + l15, DMP, kof, 15);
            c00 = MFMA16(a0, k0, c00);  c01 = MFMA16(a0, k1, c01);
            c10 = MFMA16(a1, k0, c10);  c11 = MFMA16(a1, k1, c11);
        }
        const float scl = 0.08838834764831845f;
        #pragma unroll
        for (int r = 0; r < 4; ++r) {
            int pr = lq * 4 + r;
            int qc = l15;
            rC.p.s.sc[bi][pr][qc] = c00[r] * scl;
            if (qc + 16 < N_PERM) rC.p.s.sc[bi][pr][qc + 16] = c01[r] * scl;
            if (pr + 16 < N_PERM) {
                rC.p.s.sc[bi][pr + 16][qc] = c10[r] * scl;
                if (qc + 16 < N_PERM) rC.p.s.sc[bi][pr + 16][qc + 16] = c11[r] * scl;
            }
        }
    }
    __syncthreads();

    // ---- stage 6: row softmax, then column sums ----
    if (tid < TB * N_PERM) {
        int bi = tid / N_PERM, row = tid % N_PERM;
        float* scrow = rC.p.s.sc[bi][row];
        float mx = -1e30f;
        #pragma unroll
        for (int qq = 0; qq < N_PERM; ++qq) mx = fmaxf(mx, scrow[qq]);
        float sum = 0.f;
        #pragma unroll
        for (int qq = 0; qq < N_PERM; ++qq) { float e = __expf(scrow[qq] - mx); scrow[qq] = e; sum += e; }
        float inv = 1.f / sum;
        #pragma unroll
        for (int qq = 0; qq < N_PERM; ++qq) scrow[qq] *= inv;
    }
    __syncthreads();
    if (tid < TB * N_PERM) {
        int bi = tid / N_PERM, col = tid % N_PERM;
        float cs = 0.f;
        #pragma unroll
        for (int p = 0; p < N_PERM; ++p) cs += rC.p.s.sc[bi][p][col];
        rC.p.cs[bi][col] = cs;
    }
    __syncthreads();

    // ---- stage 7: pooled = colsum(attn) @ v (swizzled v reads, 2-wide) ----
    if (tid < TB * 64) {
        int bi = tid >> 6, jp = tid & 63, j0 = jp * 2;
        float a0 = 0.f, a1 = 0.f;
        #pragma unroll
        for (int qq = 0; qq < N_PERM; ++qq) {
            int row  = bi * N_PERM + qq;
            int vcol = ((((j0 >> 3) ^ (row & 15)) << 3) | (j0 & 7));
            unsigned w = *(const unsigned*)(&rA.v[row][vcol]);
            float c = rC.p.cs[bi][qq];
            a0 += c * __uint_as_float(w << 16);
            a1 += c * __uint_as_float(w & 0xffff0000u);
        }
        bf16 t0 = f2b(a0), t1 = f2b(a1);
        unsigned pk = (unsigned)(*(const unsigned short*)&t0)
                    | ((unsigned)(*(const unsigned short*)&t1) << 16);
        int pcol = ((((j0 >> 3) ^ (bi & 15)) << 3) | (j0 & 7));
        *(unsigned*)(&rC.p.pooled[bi][pcol]) = pk;
    }
    for (int i = tid; i < (16 - TB) * 64; i += 256) {   // zero pad rows TB..15
        int row = TB + (i >> 6), c2 = (i & 63) * 2;
        *(unsigned*)(&rC.p.pooled[row][c2]) = 0u;
    }
    __syncthreads();

    // ---- stage 8: hr = relu(pooled @ Wr + br) via MFMA, swizzled pooled reads ----
    {
        s16x8 pfr[4];
        #pragma unroll
        for (int kt = 0; kt < 4; ++kt)
            pfr[kt] = frag_lds(&rC.p.pooled[0][0], l15, DMP, kt * 32 + lq * 8, 15);
        f32x4 acc[4];
        #pragma unroll
        for (int i = 0; i < 4; ++i) acc[i] = zf;
        #pragma unroll
        for (int kt = 0; kt < 4; ++kt)
            #pragma unroll
            for (int i = 0; i < 4; ++i) {
                int nt = wav * 4 + i;
                s16x8 wf = *(const s16x8*)(wp + OFF_WR + (nt * 4 + kt) * 512 + (lq * 16 + l15) * 8);
                acc[i] = MFMA16(wf, pfr[kt], acc[i]);
            }
        if (l15 < TB) {
            #pragma unroll
            for (int i = 0; i < 4; ++i) {
                int n0 = (wav * 4 + i) * 16 + lq * 4;
                f32x4 bs = *(const f32x4*)(brv + n0);
                f32x4 o;
                #pragma unroll
                for (int r = 0; r < 4; ++r) o[r] = fmaxf(acc[i][r] + bs[r], 0.f);
                *(f32x4*)(&rC.p.hr[l15][n0]) = o;
            }
        }
    }
    __syncthreads();

    // ---- stage 9: heads, 16-way split-K (red[16][17] pads conflicts away) ----
    {
        int o = tid & 15, cch = tid >> 4;
        int bi = o >> 3, rr = o & 7;
        bool is_mean = rr < ACT;
        int a = rr & (ACT - 1);
        const float* W = is_mean ? Wm : Wsc;
        float part = 0.f;
        int k0 = cch * 16;
        #pragma unroll 8
        for (int kk = k0; kk < k0 + 16; ++kk) part += rC.p.hr[bi][kk] * W[kk * ACT + a];
        rC.p.s.red[o][cch] = part;
    }
    __syncthreads();
    if (tid < 16) {
        int bi = tid >> 3, rr = tid & 7;
        bool is_mean = rr < ACT;
        int a = rr & (ACT - 1);
        float acc = is_mean ? bm[a] : bsv[a];
        #pragma unroll
        for (int c = 0; c < 16; ++c) acc += rC.p.s.red[tid][c];
        if (!is_mean) acc = fminf(fmaxf(acc, -20.f), 2.f);
        out[(is_mean ? 0 : BATCH * ACT) + (b0 + bi) * ACT + a] = acc;
    }
}

extern "C" void kernel_launch(void* const* d_in, const int* in_sizes, int n_in,
                              void* d_out, int out_size, void* d_ws, size_t ws_size,
                              hipStream_t stream) {
    (void)in_sizes; (void)n_in; (void)out_size; (void)ws_size;
    const float* obs = (const float*)d_in[0];
    const float* ag  = (const float*)d_in[1];
    const float* g   = (const float*)d_in[2];
    const float* W1  = (const float*)d_in[3];
    const float* b1  = (const float*)d_in[4];
    const float* W2  = (const float*)d_in[5];
    const float* b2  = (const float*)d_in[6];
    const float* Wq  = (const float*)d_in[7];
    const float* bq  = (const float*)d_in[8];
    const float* Wk  = (const float*)d_in[9];
    const float* bk  = (const float*)d_in[10];
    const float* Wv  = (const float*)d_in[11];
    const float* bv  = (const float*)d_in[12];
    const float* Wr  = (const float*)d_in[13];
    const float* br  = (const float*)d_in[14];
    const float* Wm  = (const float*)d_in[15];
    const float* bm  = (const float*)d_in[16];
    const float* Ws  = (const float*)d_in[17];
    const float* bs  = (const float*)d_in[18];
    const int*  edges    = (const int*)d_in[19];
    const int*  pred_ids = (const int*)d_in[20];
    float* out = (float*)d_out;
    bf16*  wp  = (bf16*)d_ws;

    prepack_kernel<<<(PACK_TOTAL + 255) / 256, 256, 0, stream>>>(W1, b1, W2, Wq, Wk, Wv, Wr, wp);
    actor_main<<<BATCH / TB, 256, 0, stream>>>(
        obs, ag, g, b2, bq, bk, bv, br, Wm, bm, Ws, bs,
        edges, pred_ids, wp, out);
}

// Round 10
// 276.270 us; speedup vs baseline: 1.3688x; 1.3688x over previous
//
#include <hip/hip_runtime.h>
#include <hip/hip_bf16.h>

#define NB_OBJ   5
#define DIM_BODY 10
#define DIM_OBJ  15
#define N_PERM   20
#define HID      256
#define DMP      128
#define ACT      4
#define BATCH    32768
#define GOAL_DIM 30
#define DIN      19
#define OBS_LEN  85
#define TB       4                 // batch elements per block
#define MROWS    80                // TB * N_PERM, 5 M-tiles

typedef __hip_bfloat16 bf16;
typedef __attribute__((ext_vector_type(8))) short s16x8;
typedef __attribute__((ext_vector_type(4))) short s16x4;
typedef __attribute__((ext_vector_type(4))) float f32x4;

#define MFMA16(a, b, c) __builtin_amdgcn_mfma_f32_16x16x32_bf16((a), (b), (c), 0, 0, 0)

// ---- packed-weight offsets in d_ws (bf16 elements) ----
// tiled: [nt][kt][c(4)][n16(16)][j(8)] = W[kt*32+c*8+j][nt*16+n16]
#define OFF_W1   0          // NT=16, KT=1 -> 8192 (k=19 row = b1 bias fold)
#define OFF_W2   8192       // NT=8,  KT=8 -> 32768
#define OFF_M    40960      // NT=8,  KT=4 -> 16384   M = Wq Wk^T / sqrt(128)
#define OFF_WV   57344      // NT=8,  KT=4 -> 16384
#define OFF_WR   73728      // NT=16, KT=4 -> 32768
#define OFF_WP   106496     // 128 floats (w' = Wk bq / sqrt(128)) as raw f32
#define PACK_TOTAL 106624   // thread count for prepack

__device__ __forceinline__ bf16 f2b(float x) { return __float2bfloat16(x); }

// XOR block swizzle: element [m][k] at column ((k>>3)^(m&bprm))*8 + (k&7)
__device__ __forceinline__ s16x8 frag_lds(const bf16* base, int m, int stride, int kof, int bprm) {
    int phys = (((kof >> 3) ^ (m & bprm)) << 3);
    return *(const s16x8*)(base + m * stride + phys);
}

// C^T epilogue: lane owns fixed m, regs = 4 consecutive n -> one b64 write
__device__ __forceinline__ void store_c4(bf16* base, int m, int stride, int n0,
                                         int bprm, f32x4 acc, f32x4 bs, bool do_relu) {
    s16x4 w;
    #pragma unroll
    for (int r = 0; r < 4; ++r) {
        float v = acc[r] + bs[r];
        if (do_relu) v = fmaxf(v, 0.f);
        bf16 t = f2b(v);
        w[r] = *(const short*)&t;
    }
    int blk = ((n0 >> 3) ^ (m & bprm));
    *(s16x4*)(base + m * stride + blk * 8 + (n0 & 7)) = w;
}

// ================= prepack =================
__device__ __forceinline__ void pack_tiled(const float* __restrict__ W, int Kact, int N,
                                           int KT, bf16* __restrict__ dst, int idx) {
    int tile = idx >> 9;
    int r    = idx & 511;
    int kt   = tile % KT, nt = tile / KT;
    int c    = r >> 7;
    int rem  = r & 127;
    int n16  = rem >> 3, j = rem & 7;
    int k    = kt * 32 + c * 8 + j;
    float v  = (k < Kact) ? W[k * N + nt * 16 + n16] : 0.f;
    dst[idx] = __float2bfloat16(v);
}

__global__ __launch_bounds__(256) void prepack_kernel(
    const float* __restrict__ W1, const float* __restrict__ b1,
    const float* __restrict__ W2,
    const float* __restrict__ Wq, const float* __restrict__ bq,
    const float* __restrict__ Wk,
    const float* __restrict__ Wv, const float* __restrict__ Wr,
    bf16* __restrict__ ws) {
    const float scl = 0.08838834764831845f;   // 1/sqrt(128)
    int idx = blockIdx.x * 256 + threadIdx.x;
    if (idx < 8192) {               // W1 with bias folded into k=19
        int nt = idx >> 9, r = idx & 511;
        int c = r >> 7, rem = r & 127, n16 = rem >> 3, j = rem & 7;
        int k = c * 8 + j, n = nt * 16 + n16;
        float v = (k < DIN) ? W1[k * HID + n] : (k == DIN ? b1[n] : 0.f);
        ws[OFF_W1 + idx] = __float2bfloat16(v);
    }
    else if (idx < 40960) pack_tiled(W2, 256, 128, 8, ws + OFF_W2, idx - 8192);
    else if (idx < 57344) {         // M = Wq Wk^T * scl, fragment-tiled (KT=4)
        int i2 = idx - 40960;
        int tile = i2 >> 9, r = i2 & 511;
        int kt = tile & 3, nt = tile >> 2;
        int c = r >> 7, rem = r & 127, n16 = rem >> 3, j = rem & 7;
        int d = kt * 32 + c * 8 + j;        // contraction dim of t = x@M
        int e = nt * 16 + n16;              // output dim
        float s = 0.f;
        for (int j2 = 0; j2 < DMP; ++j2) s += Wq[d * DMP + j2] * Wk[e * DMP + j2];
        ws[OFF_M + i2] = __float2bfloat16(s * scl);
    }
    else if (idx < 73728)  pack_tiled(Wv, 128, 128, 4, ws + OFF_WV, idx - 57344);
    else if (idx < 106496) pack_tiled(Wr, 128, 256, 4, ws + OFF_WR, idx - 73728);
    else if (idx < PACK_TOTAL) {    // w'[d] = scl * sum_j Wk[d][j] bq[j], fp32
        int d = idx - OFF_WP;
        float s = 0.f;
        for (int j2 = 0; j2 < DMP; ++j2) s += Wk[d * DMP + j2] * bq[j2];
        ((float*)(ws + OFF_WP))[d] = s * scl;
    }
}

// ================= main fused kernel =================
// LDS: rA 10,816 + rB 20,480 + rC 20,480 = 51,776 B -> 3 blocks/CU
__global__ __launch_bounds__(256, 3) void actor_main(
    const float* __restrict__ obs, const float* __restrict__ ag, const float* __restrict__ g,
    const float* __restrict__ b2v, const float* __restrict__ bvv, const float* __restrict__ brv,
    const float* __restrict__ Wm, const float* __restrict__ bm,
    const float* __restrict__ Wsc, const float* __restrict__ bsv,
    const int* __restrict__ edges, const int* __restrict__ pred_ids,
    const bf16* __restrict__ wp, float* __restrict__ out)
{
    const int b0   = blockIdx.x * TB;
    const int tid  = threadIdx.x;
    const int lane = tid & 63;
    const int wav  = tid >> 6;
    const int l15  = lane & 15;
    const int lq   = lane >> 4;

    __shared__ __align__(16) union {              // 10,816 B
        struct {
            float obs_[TB][OBS_LEN];
            float dg[TB][GOAL_DIM];
            int   edg[N_PERM * 2];
            int   prd[N_PERM * 3];
            bf16  inp[MROWS][40];                 // K pad 19->32 (+1.0 bias col)
        } a;                                      // 8,640 (dead after MLP1 phase b)
        struct {
            union { float sc[TB][N_PERM][N_PERM]; bf16 y[16][DMP]; } s;
            float cs[TB][N_PERM];
            bf16  pooled[16][DMP];                // swizzled
        } p;                                      // 10,816
    } rA;
    __shared__ __align__(16) union {              // 20,480 B
        bf16 hall[MROWS][DMP];                    // one 128-col half of MLP1 out
        bf16 t[MROWS][DMP];                       // t = x@M + w' (after MLP2)
    } rB;
    __shared__ __align__(16) union {              // 20,480 B
        bf16 x[MROWS][DMP];                       // edge_feat (dead after y)
        struct { float hr[TB][HID]; float red[32][9]; } h;
    } rC;

    const f32x4 zf = {0.f, 0.f, 0.f, 0.f};

    // ---- stage 0: inputs -> LDS ----
    for (int i = tid; i < TB * OBS_LEN; i += 256)
        ((float*)rA.a.obs_)[i] = obs[b0 * OBS_LEN + i];
    if (tid < TB * GOAL_DIM) ((float*)rA.a.dg)[tid] = g[b0 * GOAL_DIM + tid] - ag[b0 * GOAL_DIM + tid];
    if (tid < N_PERM * 2)    rA.a.edg[tid] = edges[tid];
    if (tid < N_PERM * 3)    rA.a.prd[tid] = pred_ids[tid];
    __syncthreads();

    // ---- stage 1: build 80 x 32 edge inputs (col 19 = 1.0 bias) ----
    for (int idx = tid; idx < MROWS * 32; idx += 256) {
        int m = idx >> 5, c = idx & 31;
        int bi = m / N_PERM, p = m - bi * N_PERM;
        float v = 0.f;
        if      (c < 10) v = rA.a.obs_[bi][c];
        else if (c < 13) v = rA.a.dg[bi][rA.a.prd[p * 3 + (c - 10)]];
        else if (c < 16) v = rA.a.obs_[bi][DIM_BODY + rA.a.edg[p * 2 + 0] * DIM_OBJ + (c - 13)];
        else if (c < 19) v = rA.a.obs_[bi][DIM_BODY + rA.a.edg[p * 2 + 1] * DIM_OBJ + (c - 16)];
        else if (c == 19) v = 1.0f;
        rA.a.inp[m][c] = f2b(v);
    }
    __syncthreads();

    // MLP1 input fragments (live across both phases)
    s16x8 xfr[5];
    #pragma unroll
    for (int mt = 0; mt < 5; ++mt)
        xfr[mt] = *(const s16x8*)(&rA.a.inp[mt * 16 + l15][lq * 8]);

    // MLP2 accumulators (live across both phases)
    f32x4 m2a[5], m2b[5];
    #pragma unroll
    for (int mt = 0; mt < 5; ++mt) { m2a[mt] = zf; m2b[mt] = zf; }
    const int nt0 = wav * 2, nt1 = nt0 + 1;

    // ---- two-phase MLP1 (19->256) + MLP2 (256->128), hall = 128-col half ----
    #pragma unroll
    for (int ph = 0; ph < 2; ++ph) {
        #pragma unroll
        for (int ntl = 0; ntl < 2; ++ntl) {
            int ntg = ph * 8 + wav * 2 + ntl;     // global nt 0..15
            s16x8 wfr = *(const s16x8*)(wp + OFF_W1 + ntg * 512 + (lq * 16 + l15) * 8);
            int nloc = (wav * 2 + ntl) * 16 + lq * 4;   // col within half
            #pragma unroll
            for (int mt = 0; mt < 5; ++mt) {
                f32x4 acc = MFMA16(wfr, xfr[mt], zf);
                store_c4(&rB.hall[0][0], mt * 16 + l15, DMP, nloc, 15, acc, zf, true);
            }
        }
        __syncthreads();
        #pragma unroll
        for (int ktl = 0; ktl < 4; ++ktl) {
            int ktg = ph * 4 + ktl;
            s16x8 wf0 = *(const s16x8*)(wp + OFF_W2 + (nt0 * 8 + ktg) * 512 + (lq * 16 + l15) * 8);
            s16x8 wf1 = *(const s16x8*)(wp + OFF_W2 + (nt1 * 8 + ktg) * 512 + (lq * 16 + l15) * 8);
            #pragma unroll
            for (int mt = 0; mt < 5; ++mt) {
                s16x8 a = frag_lds(&rB.hall[0][0], mt * 16 + l15, DMP, ktl * 32 + lq * 8, 15);
                m2a[mt] = MFMA16(wf0, a, m2a[mt]);
                m2b[mt] = MFMA16(wf1, a, m2b[mt]);
            }
        }
        __syncthreads();   // hall reads done before next-phase overwrite
    }
    // MLP2 epilogue -> x
    {
        f32x4 bs0 = *(const f32x4*)(b2v + nt0 * 16 + lq * 4);
        f32x4 bs1 = *(const f32x4*)(b2v + nt1 * 16 + lq * 4);
        #pragma unroll
        for (int mt = 0; mt < 5; ++mt) {
            int m = mt * 16 + l15;
            store_c4(&rC.x[0][0], m, DMP, nt0 * 16 + lq * 4, 15, m2a[mt], bs0, true);
            store_c4(&rC.x[0][0], m, DMP, nt1 * 16 + lq * 4, 15, m2b[mt], bs1, true);
        }
    }
    __syncthreads();

    // ---- stage 4: t = x@M + w' (Q/K folded; 1/sqrt(128) inside M,w') ----
    {
        const float* wf = (const float*)(wp + OFF_WP);
        f32x4 a0[5], a1[5];
        #pragma unroll
        for (int mt = 0; mt < 5; ++mt) { a0[mt] = zf; a1[mt] = zf; }
        #pragma unroll
        for (int kt = 0; kt < 4; ++kt) {
            s16x8 wf0 = *(const s16x8*)(wp + OFF_M + (nt0 * 4 + kt) * 512 + (lq * 16 + l15) * 8);
            s16x8 wf1 = *(const s16x8*)(wp + OFF_M + (nt1 * 4 + kt) * 512 + (lq * 16 + l15) * 8);
            #pragma unroll
            for (int mt = 0; mt < 5; ++mt) {
                s16x8 a = frag_lds(&rC.x[0][0], mt * 16 + l15, DMP, kt * 32 + lq * 8, 15);
                a0[mt] = MFMA16(wf0, a, a0[mt]);
                a1[mt] = MFMA16(wf1, a, a1[mt]);
            }
        }
        f32x4 bs0 = *(const f32x4*)(wf + nt0 * 16 + lq * 4);
        f32x4 bs1 = *(const f32x4*)(wf + nt1 * 16 + lq * 4);
        #pragma unroll
        for (int mt = 0; mt < 5; ++mt) {
            int m = mt * 16 + l15;
            store_c4(&rB.t[0][0], m, DMP, nt0 * 16 + lq * 4, 15, a0[mt], bs0, false);
            store_c4(&rB.t[0][0], m, DMP, nt1 * 16 + lq * 4, 15, a1[mt], bs1, false);
        }
    }
    __syncthreads();

    // ---- stage 5: scores'[p][q] = t_p . x_q  (wave = batch elem) ----
    {
        const int bi = wav;
        const int r0 = bi * N_PERM;
        f32x4 c00 = zf, c01 = zf, c10 = zf, c11 = zf;
        #pragma unroll
        for (int kt = 0; kt < 4; ++kt) {
            int kof = kt * 32 + lq * 8;
            s16x8 a0 = frag_lds(&rB.t[0][0], r0 + l15,      DMP, kof, 15);
            s16x8 a1 = frag_lds(&rB.t[0][0], r0 + 16 + l15, DMP, kof, 15);  // rows>79 garbage, masked
            s16x8 k0 = frag_lds(&rC.x[0][0], r0 + l15,      DMP, kof, 15);
            s16x8 k1 = frag_lds(&rC.x[0][0], r0 + 16 + l15, DMP, kof, 15);
            c00 = MFMA16(a0, k0, c00);  c01 = MFMA16(a0, k1, c01);
            c10 = MFMA16(a1, k0, c10);  c11 = MFMA16(a1, k1, c11);
        }
        #pragma unroll
        for (int r = 0; r < 4; ++r) {
            int pr = lq * 4 + r, qc = l15;
            rA.p.s.sc[bi][pr][qc] = c00[r];
            if (qc + 16 < N_PERM) rA.p.s.sc[bi][pr][qc + 16] = c01[r];
            if (pr + 16 < N_PERM) {
                rA.p.s.sc[bi][pr + 16][qc] = c10[r];
                if (qc + 16 < N_PERM) rA.p.s.sc[bi][pr + 16][qc + 16] = c11[r];
            }
        }
    }
    __syncthreads();

    // ---- stage 6: row softmax, then column sums ----
    if (tid < TB * N_PERM) {
        int bi = tid / N_PERM, row = tid % N_PERM;
        float* scrow = rA.p.s.sc[bi][row];
        float mx = -1e30f;
        #pragma unroll
        for (int qq = 0; qq < N_PERM; ++qq) mx = fmaxf(mx, scrow[qq]);
        float sum = 0.f;
        #pragma unroll
        for (int qq = 0; qq < N_PERM; ++qq) { float e = __expf(scrow[qq] - mx); scrow[qq] = e; sum += e; }
        float inv = 1.f / sum;
        #pragma unroll
        for (int qq = 0; qq < N_PERM; ++qq) scrow[qq] *= inv;
    }
    __syncthreads();
    if (tid < TB * N_PERM) {
        int bi = tid / N_PERM, col = tid % N_PERM;
        float cs = 0.f;
        #pragma unroll
        for (int p = 0; p < N_PERM; ++p) cs += rA.p.s.sc[bi][p][col];
        rA.p.cs[bi][col] = cs;
    }
    __syncthreads();

    // ---- stage 7: y[bi] = sum_q cs[q] * x[bi*20+q]  (V-GEMM eliminated) ----
    {
        int bi = tid >> 6, jp = tid & 63, j0 = jp * 2;
        float a0 = 0.f, a1 = 0.f;
        #pragma unroll
        for (int qq = 0; qq < N_PERM; ++qq) {
            int row  = bi * N_PERM + qq;
            int vcol = ((((j0 >> 3) ^ (row & 15)) << 3) | (j0 & 7));
            unsigned w = *(const unsigned*)(&rC.x[row][vcol]);
            float c = rA.p.cs[bi][qq];
            a0 += c * __uint_as_float(w << 16);
            a1 += c * __uint_as_float(w & 0xffff0000u);
        }
        bf16 t0 = f2b(a0), t1 = f2b(a1);
        unsigned pk = (unsigned)(*(const unsigned short*)&t0)
                    | ((unsigned)(*(const unsigned short*)&t1) << 16);
        int pcol = ((((j0 >> 3) ^ (bi & 15)) << 3) | (j0 & 7));
        *(unsigned*)(&rA.p.s.y[bi][pcol]) = pk;
    }
    __syncthreads();

    // ---- stage 7.5: pooled = y@Wv + 20*bv (one M-tile) ----
    {
        s16x8 pfr[4];
        #pragma unroll
        for (int kt = 0; kt < 4; ++kt)
            pfr[kt] = frag_lds(&rA.p.s.y[0][0], l15, DMP, kt * 32 + lq * 8, 15);
        f32x4 acc0 = zf, acc1 = zf;
        #pragma unroll
        for (int kt = 0; kt < 4; ++kt) {
            s16x8 wf0 = *(const s16x8*)(wp + OFF_WV + (nt0 * 4 + kt) * 512 + (lq * 16 + l15) * 8);
            s16x8 wf1 = *(const s16x8*)(wp + OFF_WV + (nt1 * 4 + kt) * 512 + (lq * 16 + l15) * 8);
            acc0 = MFMA16(wf0, pfr[kt], acc0);
            acc1 = MFMA16(wf1, pfr[kt], acc1);
        }
        f32x4 bs0 = *(const f32x4*)(bvv + nt0 * 16 + lq * 4);
        f32x4 bs1 = *(const f32x4*)(bvv + nt1 * 16 + lq * 4);
        #pragma unroll
        for (int r = 0; r < 4; ++r) { bs0[r] *= 20.f; bs1[r] *= 20.f; }
        store_c4(&rA.p.pooled[0][0], l15, DMP, nt0 * 16 + lq * 4, 15, acc0, bs0, false);
        store_c4(&rA.p.pooled[0][0], l15, DMP, nt1 * 16 + lq * 4, 15, acc1, bs1, false);
    }
    __syncthreads();

    // ---- stage 8: hr = relu(pooled@Wr + br); x dead -> hr region ----
    {
        s16x8 pfr[4];
        #pragma unroll
        for (int kt = 0; kt < 4; ++kt)
            pfr[kt] = frag_lds(&rA.p.pooled[0][0], l15, DMP, kt * 32 + lq * 8, 15);
        f32x4 acc[4];
        #pragma unroll
        for (int i = 0; i < 4; ++i) acc[i] = zf;
        #pragma unroll
        for (int kt = 0; kt < 4; ++kt)
            #pragma unroll
            for (int i = 0; i < 4; ++i) {
                int nt = wav * 4 + i;
                s16x8 wf = *(const s16x8*)(wp + OFF_WR + (nt * 4 + kt) * 512 + (lq * 16 + l15) * 8);
                acc[i] = MFMA16(wf, pfr[kt], acc[i]);
            }
        if (l15 < TB) {
            #pragma unroll
            for (int i = 0; i < 4; ++i) {
                int n0 = (wav * 4 + i) * 16 + lq * 4;
                f32x4 bs = *(const f32x4*)(brv + n0);
                f32x4 o;
                #pragma unroll
                for (int r = 0; r < 4; ++r) o[r] = fmaxf(acc[i][r] + bs[r], 0.f);
                *(f32x4*)(&rC.h.hr[l15][n0]) = o;
            }
        }
    }
    __syncthreads();

    // ---- stage 9: heads. 32 outputs (4 bi x 8) x 8 split-K chunks of 32 ----
    {
        int o = tid & 31, cch = tid >> 5;     // o: output row, cch: k-chunk 0..7
        int bi = o >> 3, rr = o & 7;
        bool is_mean = rr < ACT;
        int a = rr & (ACT - 1);
        const float* W = is_mean ? Wm : Wsc;
        float part = 0.f;
        int k0 = cch * 32;
        #pragma unroll 8
        for (int kk = k0; kk < k0 + 32; ++kk) part += rC.h.hr[bi][kk] * W[kk * ACT + a];
        rC.h.red[o][cch] = part;
    }
    __syncthreads();
    if (tid < 32) {
        int bi = tid >> 3, rr = tid & 7;
        bool is_mean = rr < ACT;
        int a = rr & (ACT - 1);
        float acc = is_mean ? bm[a] : bsv[a];
        #pragma unroll
        for (int c = 0; c < 8; ++c) acc += rC.h.red[tid][c];
        if (!is_mean) acc = fminf(fmaxf(acc, -20.f), 2.f);
        out[(is_mean ? 0 : BATCH * ACT) + (b0 + bi) * ACT + a] = acc;
    }
}

extern "C" void kernel_launch(void* const* d_in, const int* in_sizes, int n_in,
                              void* d_out, int out_size, void* d_ws, size_t ws_size,
                              hipStream_t stream) {
    (void)in_sizes; (void)n_in; (void)out_size; (void)ws_size;
    const float* obs = (const float*)d_in[0];
    const float* ag  = (const float*)d_in[1];
    const float* g   = (const float*)d_in[2];
    const float* W1  = (const float*)d_in[3];
    const float* b1  = (const float*)d_in[4];
    const float* W2  = (const float*)d_in[5];
    const float* b2  = (const float*)d_in[6];
    const float* Wq  = (const float*)d_in[7];
    const float* bq  = (const float*)d_in[8];
    const float* Wk  = (const float*)d_in[9];
    const float* Wv  = (const float*)d_in[11];
    const float* bv  = (const float*)d_in[12];
    const float* Wr  = (const float*)d_in[13];
    const float* br  = (const float*)d_in[14];
    const float* Wm  = (const float*)d_in[15];
    const float* bm  = (const float*)d_in[16];
    const float* Ws  = (const float*)d_in[17];
    const float* bs  = (const float*)d_in[18];
    const int*  edges    = (const int*)d_in[19];
    const int*  pred_ids = (const int*)d_in[20];
    float* out = (float*)d_out;
    bf16*  wp  = (bf16*)d_ws;

    prepack_kernel<<<(PACK_TOTAL + 255) / 256, 256, 0, stream>>>(
        W1, b1, W2, Wq, bq, Wk, Wv, Wr, wp);
    actor_main<<<BATCH / TB, 256, 0, stream>>>(
        obs, ag, g, b2, bv, br, Wm, bm, Ws, bs,
        edges, pred_ids, wp, out);
}